// Round 4
// baseline (516.674 us; speedup 1.0000x reference)
//
#include <hip/hip_runtime.h>

#define R 256
#define C 32
#define NCELL1 32                        // cells per axis
#define NCELLS (NCELL1 * NCELL1 * NCELL1)
#define CAP 128                          // bucket capacity per cell (avg load ~61)

typedef float f32x4 __attribute__((ext_vector_type(4)));

// ---------------------------------------------------------------------------
// Convert + transpose: (3, C, R, R) f32 -> (3, R, R, C) bf16 (stored ushort).
// Side duty: first 128 blocks zero the 32K cell counters; block 128 zeros the
// overflow counter.
__global__ __launch_bounds__(256) void convert_kernel(const float* __restrict__ tri,
                                                      ushort* __restrict__ tw,
                                                      unsigned* __restrict__ cnt,
                                                      unsigned* __restrict__ ovcnt) {
    if (blockIdx.x < NCELLS / 256)
        cnt[blockIdx.x * 256 + threadIdx.x] = 0u;
    if (blockIdx.x == NCELLS / 256 && threadIdx.x == 0)
        *ovcnt = 0u;

    int p = blockIdx.x >> 8;        // blockIdx.x = p*R + y
    int y = blockIdx.x & (R - 1);
    int x = threadIdx.x;

    unsigned packed[C / 2];         // 16 dwords = 32 bf16
#pragma unroll
    for (int i = 0; i < C / 2; ++i) {
        unsigned w = 0;
#pragma unroll
        for (int h = 0; h < 2; ++h) {
            float f = tri[(((p * C + (2 * i + h)) * R) + y) * R + x];
            unsigned u = __float_as_uint(f);
            unsigned r = (u + 0x7fffu + ((u >> 16) & 1u)) >> 16;  // RNE bf16
            w |= (r & 0xffffu) << (16 * h);
        }
        packed[i] = w;
    }
    uint4* dst = (uint4*)(tw + ((size_t)(p * R + y) * R + x) * C);
#pragma unroll
    for (int i = 0; i < 4; ++i) {
        dst[i] = make_uint4(packed[4 * i], packed[4 * i + 1],
                            packed[4 * i + 2], packed[4 * i + 3]);
    }
}

// ---------------------------------------------------------------------------
// Cell id with OCTANT-major packing: top bit of each coord selects one of 8
// 16^3-cell octants; the XCD-chunked block swizzle in the sampler then maps
// octant k -> XCD k, so each XCD's plane working set is a compact 129^2-texel
// region per plane (~3.2 MiB for all 3) and stays L2-resident.
__device__ __forceinline__ int cell_of(float px, float py, float pz) {
    int cx = min(max((int)((px + 1.0f) * 16.0f), 0), NCELL1 - 1);
    int cy = min(max((int)((py + 1.0f) * 16.0f), 0), NCELL1 - 1);
    int cz = min(max((int)((pz + 1.0f) * 16.0f), 0), NCELL1 - 1);
    int oct = ((cz >> 4) << 2) | ((cy >> 4) << 1) | (cx >> 4);
    return (oct << 12) | ((cz & 15) << 8) | ((cy & 15) << 4) | (cx & 15);
}

// One pass: bump-allocate a slot in the point's cell bucket; spill to the
// overflow list if the bucket is full (statistically never for uniform data,
// but correctness does not depend on that). Bucket stores are non-temporal:
// they are write-once streaming data and must not pollute L2.
__global__ __launch_bounds__(256) void scatter_kernel(const float* __restrict__ xyz,
                                                      unsigned* __restrict__ cnt,
                                                      unsigned* __restrict__ ovcnt,
                                                      f32x4* __restrict__ buckets,
                                                      f32x4* __restrict__ ov, int M) {
    int m = blockIdx.x * 256 + threadIdx.x;
    if (m >= M) return;
    float px = xyz[3 * m + 0], py = xyz[3 * m + 1], pz = xyz[3 * m + 2];
    int cell = cell_of(px, py, pz);
    unsigned slot = atomicAdd(&cnt[cell], 1u);
    f32x4 rec = {px, py, pz, __int_as_float(m)};
    if (slot < CAP) __builtin_nontemporal_store(rec, buckets + (size_t)cell * CAP + slot);
    else            ov[atomicAdd(ovcnt, 1u)] = rec;
}

// ---------------------------------------------------------------------------
// One tap's 8 channels (4 dwords of packed bf16) into 8 accumulators.
__device__ __forceinline__ void tap_fma(uint4 v, float w, float* acc) {
    unsigned d[4] = {v.x, v.y, v.z, v.w};
#pragma unroll
    for (int k = 0; k < 4; ++k) {
        acc[2 * k]     = fmaf(w, __uint_as_float(d[k] << 16),          acc[2 * k]);
        acc[2 * k + 1] = fmaf(w, __uint_as_float(d[k] & 0xffff0000u), acc[2 * k + 1]);
    }
}

// Core sampling for one point; writes out[mo*C + 8*cq .. +8).
// Tap loads are CACHED (plane reuse is the whole point); out stores are
// non-temporal (write-once, would otherwise evict the planes from L2).
__device__ __forceinline__ void sample_point(float px, float py, float pz, int mo,
                                             const ushort* __restrict__ twc,
                                             float* __restrict__ out, int cq) {
    float uu[3] = {py, pz, py};
    float vv[3] = {px, px, pz};

    float acc[8];
#pragma unroll
    for (int j = 0; j < 8; ++j) acc[j] = 0.0f;

#pragma unroll
    for (int p = 0; p < 3; ++p) {
        float ix = (uu[p] + 1.0f) * 0.5f * 255.0f;
        float iy = (vv[p] + 1.0f) * 0.5f * 255.0f;
        int   x0 = (int)ix;                 // coords >= 0: trunc == floor
        int   y0 = (int)iy;
        float wx1 = ix - (float)x0;
        float wy1 = iy - (float)y0;
        float wx0 = 1.0f - wx1;
        float wy0 = 1.0f - wy1;
        int x1 = min(x0 + 1, R - 1);        // weight 0 when clamped
        int y1 = min(y0 + 1, R - 1);

        float w00 = wx0 * wy0, w01 = wx1 * wy0, w10 = wx0 * wy1, w11 = wx1 * wy1;

        const ushort* pl = twc + (size_t)p * R * R * C;
        uint4 v00 = *(const uint4*)(pl + (y0 * R + x0) * C);
        uint4 v01 = *(const uint4*)(pl + (y0 * R + x1) * C);
        uint4 v10 = *(const uint4*)(pl + (y1 * R + x0) * C);
        uint4 v11 = *(const uint4*)(pl + (y1 * R + x1) * C);

        tap_fma(v00, w00, acc);
        tap_fma(v01, w01, acc);
        tap_fma(v10, w10, acc);
        tap_fma(v11, w11, acc);
    }

    f32x4* o = (f32x4*)(out + (size_t)mo * C + 8 * cq);
    f32x4 o0 = {acc[0], acc[1], acc[2], acc[3]};
    f32x4 o1 = {acc[4], acc[5], acc[6], acc[7]};
    __builtin_nontemporal_store(o0, o);
    __builtin_nontemporal_store(o1, o + 1);
}

// Cell-walking sampler. Wave owns 4 consecutive cells (one quarter lx-row of
// an octant); XCD-chunked swizzle maps octant k -> XCD k so all three plane
// regions for the octant (~3.2 MiB) are L2-resident. Bucket reads are
// non-temporal streaming.
__global__ __launch_bounds__(256) void sample_cells(const f32x4* __restrict__ buckets,
                                                    const unsigned* __restrict__ cnt,
                                                    const unsigned* __restrict__ ovcnt,
                                                    const f32x4* __restrict__ ov,
                                                    const ushort* __restrict__ tw,
                                                    float* __restrict__ out) {
    int nb  = gridDim.x;                             // 2048 (multiple of 8)
    int bid = blockIdx.x;
    int swz = (bid & 7) * (nb >> 3) + (bid >> 3);    // bijective XCD chunking

    int wid  = swz * 4 + (threadIdx.x >> 6);         // global wave id
    int lane = threadIdx.x & 63;
    int quad = lane >> 2;            // 0..15
    int cq   = lane & 3;             // channel octet
    const ushort* twc = tw + 8 * cq;

    int c0 = wid * (NCELLS / (nb * 4));              // 4 cells per wave

    for (int c = c0; c < c0 + 4; ++c) {
        int n = min((int)cnt[c], CAP);
        const f32x4* bk = buckets + (size_t)c * CAP;
        for (int i = quad; i < n; i += 16) {
            f32x4 r = __builtin_nontemporal_load(bk + i);   // 4 lanes share 16 B
            sample_point(r.x, r.y, r.z, __float_as_int(r.w), twc, out, cq);
        }
    }

    // Overflow points (normally zero): generic grid-stride path.
    int nov = (int)*ovcnt;
    if (nov > 0) {
        int gq = (swz * 256 + (int)threadIdx.x) >> 2;
        int nq = (nb * 256) >> 2;
        for (int j = gq; j < nov; j += nq) {
            f32x4 r = ov[j];
            sample_point(r.x, r.y, r.z, __float_as_int(r.w), twc, out, cq);
        }
    }
}

// Fallback (unsorted) sampler, used only if workspace is too small.
__global__ __launch_bounds__(256) void sample_kernel(const float* __restrict__ xyz,
                                                     const ushort* __restrict__ tw,
                                                     float* __restrict__ out, int M) {
    int tid = blockIdx.x * 256 + threadIdx.x;
    int q   = tid >> 2;
    int cq  = tid & 3;
    int nq  = (gridDim.x * 256) >> 2;
    const ushort* twc = tw + 8 * cq;
    for (int m = q; m < M; m += nq) {
        float px = xyz[3 * m + 0], py = xyz[3 * m + 1], pz = xyz[3 * m + 2];
        sample_point(px, py, pz, m, twc, out, cq);
    }
}

// ---------------------------------------------------------------------------
extern "C" void kernel_launch(void* const* d_in, const int* in_sizes, int n_in,
                              void* d_out, int out_size, void* d_ws, size_t ws_size,
                              hipStream_t stream) {
    const float* xyz = (const float*)d_in[0];
    const float* tri = (const float*)d_in[1];  // (3, C, R, R) f32
    float* out = (float*)d_out;                // (M, C) f32

    int M = in_sizes[0] / 3;

    // Workspace: tw (12 MiB) | cnt (128 KiB) | ovcnt (128 B) | buckets (64 MiB)
    //            | ov (M * 16 B)
    size_t tw_bytes  = (size_t)3 * R * R * C * sizeof(ushort);
    size_t cnt_off   = tw_bytes;
    size_t ovc_off   = cnt_off + (size_t)NCELLS * sizeof(unsigned);
    size_t bkt_off   = ovc_off + 128;
    size_t ov_off    = bkt_off + (size_t)NCELLS * CAP * sizeof(f32x4);
    size_t need      = ov_off + (size_t)M * sizeof(f32x4);

    ushort*   tw      = (ushort*)d_ws;
    unsigned* cnt     = (unsigned*)((char*)d_ws + cnt_off);
    unsigned* ovcnt   = (unsigned*)((char*)d_ws + ovc_off);
    f32x4*    buckets = (f32x4*)((char*)d_ws + bkt_off);
    f32x4*    ov      = (f32x4*)((char*)d_ws + ov_off);

    if (ws_size >= need) {
        convert_kernel<<<3 * R, 256, 0, stream>>>(tri, tw, cnt, ovcnt);
        int mb = (M + 255) / 256;
        scatter_kernel<<<mb, 256, 0, stream>>>(xyz, cnt, ovcnt, buckets, ov, M);
        sample_cells<<<2048, 256, 0, stream>>>(buckets, cnt, ovcnt, ov, tw, out);
    } else {
        convert_kernel<<<3 * R, 256, 0, stream>>>(tri, tw, cnt, ovcnt);
        sample_kernel<<<4096, 256, 0, stream>>>(xyz, tw, out, M);
    }
}